// Round 1
// baseline (281.891 us; speedup 1.0000x reference)
//
#include <hip/hip_runtime.h>
#include <cstdint>

// Problem constants (from reference setup_inputs)
#define AH 7
#define AW 7
#define AL 7
constexpr int Bc = 2, Cc = 128, Hc = 64, Wc = 64, Lc = 32, Nc = 256;

// One block per (roi n, output grid row i). 256 threads loop over
// e = c*49 + j*7 + k  (C*AW*AL = 6272 elements) -> coalesced output stores.
__global__ __launch_bounds__(256)
void roialign3d_kernel(const float* __restrict__ feat,
                       const float* __restrict__ rois,
                       const float* __restrict__ scale_p,
                       float* __restrict__ out) {
    const int n = blockIdx.x / AH;
    const int i = blockIdx.x % AH;

    const float scale = scale_p[0];
    const float* r = rois + n * 7;
    const int   bi = (int)r[0];
    const float h1 = r[1] * scale, w1 = r[2] * scale, l1 = r[3] * scale;
    const float h2 = r[4] * scale, w2 = r[5] * scale, l2 = r[6] * scale;

    const float roi_h = fmaxf(h2 - h1 + 1.0f, 0.0f);
    const float roi_w = fmaxf(w2 - w1 + 1.0f, 0.0f);
    const float roi_l = fmaxf(l2 - l1 + 1.0f, 0.0f);
    const float sh = roi_h * (1.0f / (AH - 1));
    const float sw = roi_w * (1.0f / (AW - 1));
    const float sl = roi_l * (1.0f / (AL - 1));

    // h-direction for this block's row i (uniform across block)
    const float gh  = fminf(fmaxf(h1 + sh * (float)i, 0.0f), (float)(Hc - 1));
    const float h0f = floorf(gh);
    const float fh  = gh - h0f;
    const int   h0i = (int)h0f;
    const int   h1i = min(h0i + 1, Hc - 1);

    const float* fb = feat + (size_t)bi * Cc * Hc * Wc * Lc;

    const float* __restrict__ row0base = fb + (size_t)h0i * Wc * Lc;
    const float* __restrict__ row1base = fb + (size_t)h1i * Wc * Lc;

    float* __restrict__ outn = out + ((size_t)n * Cc) * (AH * AW * AL) + (size_t)i * (AW * AL);

    for (int e = threadIdx.x; e < Cc * AW * AL; e += 256) {
        const int k = e % AL;
        const int j = (e / AL) % AW;
        const int c = e / (AW * AL);

        const float gw  = fminf(fmaxf(w1 + sw * (float)j, 0.0f), (float)(Wc - 1));
        const float gl  = fminf(fmaxf(l1 + sl * (float)k, 0.0f), (float)(Lc - 1));
        const float w0f = floorf(gw);
        const float l0f = floorf(gl);
        const float fw  = gw - w0f;
        const float fl  = gl - l0f;
        const int   w0i = (int)w0f;
        const int   l0i = (int)l0f;
        const int   w1i = min(w0i + 1, Wc - 1);
        const int   l1i = min(l0i + 1, Lc - 1);

        const size_t coff = (size_t)c * Hc * Wc * Lc;
        const float* p00 = row0base + coff + (size_t)w0i * Lc;
        const float* p01 = row0base + coff + (size_t)w1i * Lc;
        const float* p10 = row1base + coff + (size_t)w0i * Lc;
        const float* p11 = row1base + coff + (size_t)w1i * Lc;

        const float v000 = p00[l0i], v001 = p00[l1i];
        const float v010 = p01[l0i], v011 = p01[l1i];
        const float v100 = p10[l0i], v101 = p10[l1i];
        const float v110 = p11[l0i], v111 = p11[l1i];

        const float wl1v = fl, wl0v = 1.0f - fl;
        const float a00 = v000 * wl0v + v001 * wl1v;
        const float a01 = v010 * wl0v + v011 * wl1v;
        const float a10 = v100 * wl0v + v101 * wl1v;
        const float a11 = v110 * wl0v + v111 * wl1v;

        const float b0 = a00 * (1.0f - fw) + a01 * fw;
        const float b1 = a10 * (1.0f - fw) + a11 * fw;
        const float res = b0 * (1.0f - fh) + b1 * fh;

        outn[(size_t)c * (AH * AW * AL) + j * AL + k] = res;
    }
}

extern "C" void kernel_launch(void* const* d_in, const int* in_sizes, int n_in,
                              void* d_out, int out_size, void* d_ws, size_t ws_size,
                              hipStream_t stream) {
    const float* feat    = (const float*)d_in[0];
    const float* rois    = (const float*)d_in[1];
    const float* scale_p = (const float*)d_in[2];
    float* out = (float*)d_out;

    dim3 grid(Nc * AH);
    dim3 block(256);
    roialign3d_kernel<<<grid, block, 0, stream>>>(feat, rois, scale_p, out);
}